// Round 2
// baseline (782.403 us; speedup 1.0000x reference)
//
#include <hip/hip_runtime.h>

#define TT 1024
#define DD 32
#define HH 64

typedef __fp16 h2v __attribute__((ext_vector_type(2)));
typedef _Float16 f16x8 __attribute__((ext_vector_type(8)));
typedef float f32x4 __attribute__((ext_vector_type(4)));
typedef unsigned long long u64;

struct __attribute__((aligned(16))) H4 { h2v p[4]; };
struct __attribute__((aligned(16))) U2 { u64 a, b; };

__device__ __forceinline__ h2v pk(float a, float b) {
    return __builtin_amdgcn_cvt_pkrtz(a, b);
}
__device__ __forceinline__ float fsig(float x) {
    float e = __builtin_amdgcn_exp2f(-1.4426950408889634f * x);
    return __builtin_amdgcn_rcpf(1.0f + e);
}
__device__ __forceinline__ float ftanh(float x) {
    float e = __builtin_amdgcn_exp2f(2.885390081777927f * x);
    return 1.0f - 2.0f * __builtin_amdgcn_rcpf(1.0f + e);
}
__device__ __forceinline__ float pick4(f32x4 c, bool s0, bool s1) {
    float lo = s0 ? c[1] : c[0];
    float hi = s0 ? c[3] : c[2];
    return s1 ? hi : lo;
}
__device__ __forceinline__ f16x8 load_afrag(const float* p) {
    float4 f0 = *(const float4*)p;
    float4 f1 = *(const float4*)(p + 4);
    H4 t;
    t.p[0] = pk(f0.x, f0.y); t.p[1] = pk(f0.z, f0.w);
    t.p[2] = pk(f1.x, f1.y); t.p[3] = pk(f1.z, f1.w);
    return __builtin_bit_cast(f16x8, t);
}
__device__ __forceinline__ f16x8 mkfrag(u64 lo, u64 hi) {
    U2 t{lo, hi};
    return __builtin_bit_cast(f16x8, t);
}
__device__ __forceinline__ u64 gld(const __fp16* p) {
    return __hip_atomic_load((const u64*)p, __ATOMIC_RELAXED,
                             __HIP_MEMORY_SCOPE_AGENT);
}
#define MFMA16(A, B, C) __builtin_amdgcn_mfma_f32_16x16x32_f16(A, B, C, 0, 0, 0)

// ---------------------------------------------------------------------------
// R18: de-lockstep L1/L2. 128 blocks x 256 thr (4 waves).
//  blocks 0-63  = L1 for batch-group grp: R17's L1 pipeline, 4-wave barrier.
//    h1(t) -> LDS ring (own recurrence) AND device-coherent dword stores into
//    h1g[t][grp] (full-size, no reuse). prog[grp]=t published every 8 steps
//    (stores already retired by the step-end barrier's vmcnt drain).
//  blocks 64-127 = L2 for grp: trails L1 by ~12-20 steps (amortized spin each
//    8 steps). h1(tau) read via device-scope u64 loads prefetched ONE FULL
//    STEP ahead into regs (no LDS, no per-step sync for the L1->L2 edge).
//    Per step: PRE = bias + W_ih_l1 @ h1 (reg-resident), POST = W_hh_l1 @
//    h2(tau-1) from own 4-slot LDS ring, act, 4-wave barrier.
//  Math order identical to R17 -> bitwise-identical h1/h2/out.
//  Workspace: prog 64 ints @ +0; h1g f16[TT][64][2][4][4][8] @ +256
//  (33.6 MB; layout = the old LDS chunk layout, so lane offsets are shared).
//  Co-residency: 128 blocks <= 256 CUs, and L1 never waits on L2 -> no
//  deadlock regardless of dispatch order.
// ---------------------------------------------------------------------------
__global__ __launch_bounds__(256) void lstm2_split(
    const float* __restrict__ x,
    const float* __restrict__ w_ih_l0, const float* __restrict__ w_hh_l0,
    const float* __restrict__ b_ih_l0, const float* __restrict__ b_hh_l0,
    const float* __restrict__ w_ih_l1, const float* __restrict__ w_hh_l1,
    const float* __restrict__ b_ih_l1, const float* __restrict__ b_hh_l1,
    const float* __restrict__ w_fc,   const float* __restrict__ b_fc,
    float* __restrict__ out,
    int* __restrict__ prog, __fp16* __restrict__ h1g)
{
    const int role = blockIdx.x >> 6;       // 0 = L1, 1 = L2
    const int grp  = blockIdx.x & 63;
    const int bbase = grp * 4;
    const int tid  = threadIdx.x;
    const int wave = tid >> 6;              // 0..3
    const int lane = tid & 63;
    const int js   = wave;
    const int quad = lane >> 4;
    const int bb   = lane & 3;
    const int rsel = (lane >> 2) & 3;
    const int jj   = js*16 + quad*4 + rsel;
    const int mrow = lane & 15;
    const bool s0 = (rsel & 1) != 0;
    const bool s1 = (rsel & 2) != 0;
    const int roff = (bb*4 + quad)*8;       // B-frag read offset within a chunk

    __shared__ __attribute__((aligned(16))) __fp16 buf[1536];

    {   // zero-init 768 dwords
        int* bi = (int*)buf;
        bi[tid] = 0; bi[256 + tid] = 0; bi[512 + tid] = 0;
    }
    __syncthreads();

    float cst = 0.0f;

    if (role == 0) {
        // ================= L1 block =================
        f16x8 A[12];
        f32x4 bv0, bv1, bv2, bv3;
        #pragma unroll
        for (int q = 0; q < 4; ++q) {
            const int g = q*64 + js*16 + mrow;
            A[q*3 + 0] = load_afrag(w_ih_l0 + (size_t)g*DD + quad*8);
            A[q*3 + 1] = load_afrag(w_hh_l0 + (size_t)g*HH + quad*8);
            A[q*3 + 2] = load_afrag(w_hh_l0 + (size_t)g*HH + 32 + quad*8);
        }
        #pragma unroll
        for (int r = 0; r < 4; ++r) {
            const int j4 = js*16 + quad*4 + r;
            bv0[r] = b_ih_l0[0*64 + j4] + b_hh_l0[0*64 + j4];
            bv1[r] = b_ih_l0[1*64 + j4] + b_hh_l0[1*64 + j4];
            bv2[r] = b_ih_l0[2*64 + j4] + b_hh_l0[2*64 + j4];
            bv3[r] = b_ih_l0[3*64 + j4] + b_hh_l0[3*64 + j4];
        }
        // LDS slot = 384 f16: x chunk @ +0, h1 chunks @ +128,+256
        const int whoff = 128 + (((jj>>5)*4 + bb)*4 + ((jj&31)>>3))*8 + (jj&7);
        // global h1 store: even-rsel lane stores dword pair (jj, jj+1)
        const bool do_st = ((rsel & 1) == 0);
        const int gdw = ((jj>>5)*4 + bb)*16 + ((jj&31)>>3)*4 + ((jj&7)>>1);
        unsigned int* h1gw = (unsigned int*)h1g + grp*128 + gdw;

        const float* xg = x + (size_t)(bbase + (lane >> 4))*(TT*DD) + (lane & 15)*2;
        const int sdw = ((lane>>4)*4 + ((lane&15)>>2))*4 + ((lane&15)&3);
        float2 xv1 = {0.f, 0.f}, xv2 = {0.f, 0.f};

        if (wave == 0) {
            float2 v0 = *(const float2*)xg;
            ((int*)(buf + 0*384))[sdw] = __builtin_bit_cast(int, pk(v0.x, v0.y));
            float2 v1 = *(const float2*)(xg + DD);
            ((int*)(buf + 1*384))[sdw] = __builtin_bit_cast(int, pk(v1.x, v1.y));
            xv1 = *(const float2*)(xg + 2*DD);
            xv2 = *(const float2*)(xg + 3*DD);
        }
        __syncthreads();

        f32x4 Ca0, Ca1, Ca2, Ca3, Cb0, Cb1, Cb2, Cb3;
        {   // prologue: Ca = bias + W_ih*x(0)
            f16x8 B0 = *(const f16x8*)(buf + 0*384 + roff);
            Ca0 = MFMA16(A[0], B0, bv0);
            Ca1 = MFMA16(A[3], B0, bv1);
            Ca2 = MFMA16(A[6], B0, bv2);
            Ca3 = MFMA16(A[9], B0, bv3);
            Cb0 = bv0; Cb1 = bv1; Cb2 = bv2; Cb3 = bv3;
        }

#define L1STEP(K, P0,P1,P2,P3, Q0,Q1,Q2,Q3)                                   \
    {   const int t = tb + (K);                                               \
        if (tid == 0 && (t & 7) == 0 && t)                                    \
            __hip_atomic_store(prog + grp, t, __ATOMIC_RELEASE,               \
                               __HIP_MEMORY_SCOPE_AGENT);                     \
        if (wave == 0 && (t + 2 < TT)) {                                      \
            ((int*)(buf + (((K)+2)&3)*384))[sdw] =                            \
                __builtin_bit_cast(int, pk(xv1.x, xv1.y));                    \
            xv1 = xv2;                                                        \
            const int tl = (t + 4 < TT) ? (t + 4) : (TT - 1);                 \
            xv2 = *(const float2*)(xg + (size_t)tl*DD);                       \
        }                                                                     \
        {   const __fp16* bp = buf + (((K)-1)&3)*384;                         \
            f16x8 B1 = *(const f16x8*)(bp + 128 + roff);                      \
            f16x8 B2 = *(const f16x8*)(bp + 256 + roff);                      \
            P0 = MFMA16(A[1],  B1, P0); P0 = MFMA16(A[2],  B2, P0);           \
            P1 = MFMA16(A[4],  B1, P1); P1 = MFMA16(A[5],  B2, P1);           \
            P2 = MFMA16(A[7],  B1, P2); P2 = MFMA16(A[8],  B2, P2);           \
            P3 = MFMA16(A[10], B1, P3); P3 = MFMA16(A[11], B2, P3);           \
            float Si = pick4(P0, s0, s1);                                     \
            float Sf = pick4(P1, s0, s1);                                     \
            float Sg = pick4(P2, s0, s1);                                     \
            float So = pick4(P3, s0, s1);                                     \
            float ii = fsig(Si), ff = fsig(Sf), oo = fsig(So);                \
            float gg = ftanh(Sg);                                             \
            cst = ff * cst + ii * gg;                                         \
            float hv = oo * ftanh(cst);                                       \
            __fp16 hh_ = (__fp16)hv;                                          \
            buf[((K)&3)*384 + whoff] = hh_;                                   \
            unsigned int us = (unsigned int)__builtin_bit_cast(               \
                                  unsigned short, hh_);                       \
            unsigned int pu = (unsigned int)__shfl_xor((int)us, 4);           \
            if (do_st)                                                        \
                __hip_atomic_store(h1gw + (size_t)t*8192,                     \
                                   us | (pu << 16), __ATOMIC_RELAXED,         \
                                   __HIP_MEMORY_SCOPE_AGENT);                 \
        }                                                                     \
        if (t < TT - 1) {                                                     \
            f16x8 B0 = *(const f16x8*)(buf + (((K)+1)&3)*384 + roff);         \
            Q0 = MFMA16(A[0], B0, bv0);                                       \
            Q1 = MFMA16(A[3], B0, bv1);                                       \
            Q2 = MFMA16(A[6], B0, bv2);                                       \
            Q3 = MFMA16(A[9], B0, bv3);                                       \
        }                                                                     \
        __syncthreads();                                                      \
    }

        for (int tb = 0; tb < TT; tb += 4) {
            L1STEP(0, Ca0,Ca1,Ca2,Ca3, Cb0,Cb1,Cb2,Cb3)
            L1STEP(1, Cb0,Cb1,Cb2,Cb3, Ca0,Ca1,Ca2,Ca3)
            L1STEP(2, Ca0,Ca1,Ca2,Ca3, Cb0,Cb1,Cb2,Cb3)
            L1STEP(3, Cb0,Cb1,Cb2,Cb3, Ca0,Ca1,Ca2,Ca3)
        }
#undef L1STEP
        if (tid == 0)
            __hip_atomic_store(prog + grp, TT, __ATOMIC_RELEASE,
                               __HIP_MEMORY_SCOPE_AGENT);
    } else {
        // ================= L2 block =================
        f16x8 A[16];
        f32x4 bv0, bv1, bv2, bv3;
        #pragma unroll
        for (int q = 0; q < 4; ++q) {
            const int g = q*64 + js*16 + mrow;
            A[q*4 + 0] = load_afrag(w_ih_l1 + (size_t)g*HH + quad*8);
            A[q*4 + 1] = load_afrag(w_ih_l1 + (size_t)g*HH + 32 + quad*8);
            A[q*4 + 2] = load_afrag(w_hh_l1 + (size_t)g*HH + quad*8);
            A[q*4 + 3] = load_afrag(w_hh_l1 + (size_t)g*HH + 32 + quad*8);
        }
        #pragma unroll
        for (int r = 0; r < 4; ++r) {
            const int j4 = js*16 + quad*4 + r;
            bv0[r] = b_ih_l1[0*64 + j4] + b_hh_l1[0*64 + j4];
            bv1[r] = b_ih_l1[1*64 + j4] + b_hh_l1[1*64 + j4];
            bv2[r] = b_ih_l1[2*64 + j4] + b_hh_l1[2*64 + j4];
            bv3[r] = b_ih_l1[3*64 + j4] + b_hh_l1[3*64 + j4];
        }
        // LDS slot = 256 f16: h2 chunks @ +0,+128
        const int whoff2 = (((jj>>5)*4 + bb)*4 + ((jj&31)>>3))*8 + (jj&7);
        const __fp16* h1r = h1g + grp*256 + roff;   // + tau*16384 per step

        {   const int need = 12;
            while (__hip_atomic_load(prog + grp, __ATOMIC_ACQUIRE,
                                     __HIP_MEMORY_SCOPE_AGENT) < need)
                __builtin_amdgcn_s_sleep(4);
        }
        u64 g0a, g0b, g0c, g0d, g1a = 0, g1b = 0, g1c = 0, g1d = 0;
        {   const __fp16* gp = h1r;                 // h1(0)
            g0a = gld(gp);       g0b = gld(gp + 4);
            g0c = gld(gp + 128); g0d = gld(gp + 132);
        }

#define L2STEP(K, Ga_,Gb_,Gc_,Gd_, Pa_,Pb_,Pc_,Pd_)                           \
    {   const int t = tb + (K);                                               \
        if ((t & 7) == 0 && t) {                                              \
            const int need = (t + 12 < TT) ? (t + 12) : TT;                   \
            while (__hip_atomic_load(prog + grp, __ATOMIC_ACQUIRE,            \
                                     __HIP_MEMORY_SCOPE_AGENT) < need)        \
                __builtin_amdgcn_s_sleep(4);                                  \
        }                                                                     \
        if (t + 1 < TT) {          /* prefetch h1(t+1) into other reg slot */ \
            const __fp16* gp = h1r + (size_t)(t + 1)*16384;                   \
            Pa_ = gld(gp);       Pb_ = gld(gp + 4);                           \
            Pc_ = gld(gp + 128); Pd_ = gld(gp + 132);                         \
        }                                                                     \
        f16x8 B1 = mkfrag(Ga_, Gb_);                                          \
        f16x8 B2 = mkfrag(Gc_, Gd_);                                          \
        f32x4 C0, C1, C2, C3;                                                 \
        C0 = MFMA16(A[0],  B1, bv0); C0 = MFMA16(A[1],  B2, C0);              \
        C1 = MFMA16(A[4],  B1, bv1); C1 = MFMA16(A[5],  B2, C1);              \
        C2 = MFMA16(A[8],  B1, bv2); C2 = MFMA16(A[9],  B2, C2);              \
        C3 = MFMA16(A[12], B1, bv3); C3 = MFMA16(A[13], B2, C3);              \
        {   const __fp16* bp = buf + (((K)-1)&3)*256;                         \
            f16x8 D3 = *(const f16x8*)(bp + roff);                            \
            f16x8 D4 = *(const f16x8*)(bp + 128 + roff);                      \
            C0 = MFMA16(A[2],  D3, C0); C0 = MFMA16(A[3],  D4, C0);           \
            C1 = MFMA16(A[6],  D3, C1); C1 = MFMA16(A[7],  D4, C1);           \
            C2 = MFMA16(A[10], D3, C2); C2 = MFMA16(A[11], D4, C2);           \
            C3 = MFMA16(A[14], D3, C3); C3 = MFMA16(A[15], D4, C3);           \
        }                                                                     \
        float Si = pick4(C0, s0, s1);                                         \
        float Sf = pick4(C1, s0, s1);                                         \
        float Sg = pick4(C2, s0, s1);                                         \
        float So = pick4(C3, s0, s1);                                         \
        float ii = fsig(Si), ff = fsig(Sf), oo = fsig(So);                    \
        float gg = ftanh(Sg);                                                 \
        cst = ff * cst + ii * gg;                                             \
        float hv = oo * ftanh(cst);                                           \
        buf[((K)&3)*256 + whoff2] = (__fp16)hv;                               \
        __syncthreads();                                                      \
    }

        for (int tb = 0; tb < TT; tb += 4) {
            L2STEP(0, g0a,g0b,g0c,g0d, g1a,g1b,g1c,g1d)
            L2STEP(1, g1a,g1b,g1c,g1d, g0a,g0b,g0c,g0d)
            L2STEP(2, g0a,g0b,g0c,g0d, g1a,g1b,g1c,g1d)
            L2STEP(3, g1a,g1b,g1c,g1d, g0a,g0b,g0c,g0d)
        }
#undef L2STEP

        // h2(TT-1) in slot 3. FC + sigmoid (wave 0).
        if (wave == 0) {
            const int jg = lane >> 2;
            float s = 0.f;
            #pragma unroll
            for (int u2 = 0; u2 < 4; ++u2) {
                const int j = jg*4 + u2;
                float hval = (float)buf[3*256 +
                    (((j>>5)*4 + bb)*4 + ((j&31)>>3))*8 + (j&7)];
                s += hval * w_fc[j];
            }
            s += __shfl_xor(s, 4);
            s += __shfl_xor(s, 8);
            s += __shfl_xor(s, 16);
            s += __shfl_xor(s, 32);
            if (lane < 4) out[bbase + lane] = fsig(s + b_fc[0]);
        }
    }
}

extern "C" void kernel_launch(void* const* d_in, const int* in_sizes, int n_in,
                              void* d_out, int out_size, void* d_ws, size_t ws_size,
                              hipStream_t stream) {
    // workspace: [0,256) prog counters; [256, 256+33.55MB) h1g stream
    int* prog = (int*)d_ws;
    __fp16* h1g = (__fp16*)((char*)d_ws + 256);
    hipMemsetAsync(d_ws, 0, 256, stream);
    lstm2_split<<<dim3(128), dim3(256), 0, stream>>>(
        (const float*)d_in[0],
        (const float*)d_in[1], (const float*)d_in[2],
        (const float*)d_in[3], (const float*)d_in[4],
        (const float*)d_in[5], (const float*)d_in[6],
        (const float*)d_in[7], (const float*)d_in[8],
        (const float*)d_in[9], (const float*)d_in[10],
        (float*)d_out, prog, h1g);
}